// Round 5
// baseline (565.299 us; speedup 1.0000x reference)
//
#include <hip/hip_runtime.h>
#include <hip/hip_fp16.h>

#define N_NODES   100000
#define N_EDGES   3200000
#define IN_CH     128
#define NUM_GRAPHS 1000
#define NB        391      // ceil(100000/256) buckets, 256 nodes each
#define CHUNK     4096     // edges per block in binning passes
#define NBLK_BIN  782      // ceil(3200000/4096)
#define CAP       16384    // LDS edge-staging capacity in k_build_csr

// ---------------------------------------------------------------------------
// Phase A: per-bucket edge counts (bucket = dst >> 8)
// ---------------------------------------------------------------------------
__global__ __launch_bounds__(256) void k_count_buckets(const int* __restrict__ ei,
                                                       int* __restrict__ gcount)
{
    __shared__ int h[NB];
    for (int i = threadIdx.x; i < NB; i += 256) h[i] = 0;
    __syncthreads();
    int base = blockIdx.x * CHUNK;
    int end = min(base + CHUNK, N_EDGES);
    for (int e = base + threadIdx.x; e < end; e += 256)
        atomicAdd(&h[ei[N_EDGES + e] >> 8], 1);
    __syncthreads();
    for (int i = threadIdx.x; i < NB; i += 256)
        if (h[i]) atomicAdd(&gcount[i], h[i]);
}

// ---------------------------------------------------------------------------
// Phase B: exclusive scan of 391 bucket counts -> boff; cursor = boff copy
// ---------------------------------------------------------------------------
__global__ __launch_bounds__(512) void k_scan_buckets(const int* __restrict__ gcount,
                                                      int* __restrict__ boff,
                                                      int* __restrict__ cursor)
{
    __shared__ int sh[512];
    int tid = threadIdx.x;
    int v = (tid < NB) ? gcount[tid] : 0;
    sh[tid] = v;
    __syncthreads();
    for (int off = 1; off < 512; off <<= 1) {
        int t = (tid >= off) ? sh[tid - off] : 0;
        __syncthreads();
        sh[tid] += t;
        __syncthreads();
    }
    if (tid < NB) {
        int ex = sh[tid] - v;
        boff[tid] = ex;
        cursor[tid] = ex;
    }
}

// ---------------------------------------------------------------------------
// Phase C: bucket-sorted scatter. LDS counting sort per chunk, then linear
// write-out: consecutive threads write consecutive addresses within each
// bucket run -> dense lines, good coalescing (vs 64 partial lines/wave).
// ---------------------------------------------------------------------------
__global__ __launch_bounds__(256) void k_scatter_pairs(const int* __restrict__ ei,
                                                       int* __restrict__ cursor,
                                                       int* __restrict__ pairbuf)
{
    __shared__ int h[NB];          // counts, then local cursor
    __shared__ int gbase[NB];
    __shared__ int sstart[NB + 1]; // local exclusive scan
    __shared__ int sa[512];
    __shared__ int sb[512];
    __shared__ int ebuf[CHUNK];
    int tid = threadIdx.x;
    for (int i = tid; i < NB; i += 256) h[i] = 0;
    __syncthreads();
    int base = blockIdx.x * CHUNK;
    int end = min(base + CHUNK, N_EDGES);
    int cntE = end - base;
    for (int e = base + tid; e < end; e += 256)
        atomicAdd(&h[ei[N_EDGES + e] >> 8], 1);
    __syncthreads();
    // inclusive Hillis-Steele scan over 512 (padded) with 256 threads x 2
    sa[tid]       = (tid < NB) ? h[tid] : 0;
    sa[tid + 256] = (tid + 256 < NB) ? h[tid + 256] : 0;
    __syncthreads();
    int* A = sa; int* B = sb;
    for (int off = 1; off < 512; off <<= 1) {
        int i1 = tid + 256;
        int v0 = A[tid] + ((tid >= off) ? A[tid - off] : 0);
        int v1 = A[i1]  + ((i1 >= off)  ? A[i1 - off]  : 0);
        __syncthreads();
        B[tid] = v0; B[i1] = v1;
        __syncthreads();
        int* tmp = A; A = B; B = tmp;
    }
    if (tid == 0) sstart[0] = 0;
    for (int i = tid; i < NB; i += 256) sstart[i + 1] = A[i];
    __syncthreads();
    // reserve global windows; reset h as local cursor
    for (int i = tid; i < NB; i += 256) {
        int c = sstart[i + 1] - sstart[i];
        gbase[i] = c ? atomicAdd(&cursor[i], c) : 0;
        h[i] = 0;
    }
    __syncthreads();
    // place edges bucket-sorted into ebuf
    for (int e = base + tid; e < end; e += 256) {
        int src = ei[e];
        int dst = ei[N_EDGES + e];
        int b = dst >> 8;
        int off = atomicAdd(&h[b], 1);
        ebuf[sstart[b] + off] = src | ((dst & 255) << 17);
    }
    __syncthreads();
    // linear write-out; binary search bucket per slot (~9 LDS reads)
    for (int i = tid; i < cntE; i += 256) {
        int lo = 0, hi = NB - 1;
        while (lo < hi) {
            int mid = (lo + hi + 1) >> 1;
            if (sstart[mid] <= i) lo = mid; else hi = mid - 1;
        }
        pairbuf[gbase[lo] + (i - sstart[lo])] = ebuf[i];
    }
}

// ---------------------------------------------------------------------------
// Phase D: one block per bucket -> rowptr + csr (bucket window L2-resident).
// ---------------------------------------------------------------------------
__global__ __launch_bounds__(256) void k_build_csr(const int* __restrict__ gcount,
                                                   const int* __restrict__ boff,
                                                   const int* __restrict__ pairbuf,
                                                   int* __restrict__ rowptr,
                                                   int* __restrict__ csr)
{
    __shared__ int cnt[256];
    __shared__ int scanv[256];
    __shared__ int ebuf[CAP];
    int b = blockIdx.x;
    int node0 = b << 8;
    int cntE = gcount[b];
    int base = boff[b];
    int tid = threadIdx.x;
    cnt[tid] = 0;
    __syncthreads();
    bool inLds = (cntE <= CAP);
    for (int i = tid; i < cntE; i += 256) {
        int p = pairbuf[base + i];
        if (inLds) ebuf[i] = p;
        atomicAdd(&cnt[(p >> 17) & 255], 1);
    }
    __syncthreads();
    int v = cnt[tid];
    scanv[tid] = v;
    __syncthreads();
    for (int off = 1; off < 256; off <<= 1) {
        int t = (tid >= off) ? scanv[tid - off] : 0;
        __syncthreads();
        scanv[tid] += t;
        __syncthreads();
    }
    int ex = scanv[tid] - v;           // exclusive within bucket
    int node = node0 + tid;
    if (node < N_NODES) rowptr[node] = base + ex;
    if (b == NB - 1 && tid == 0) rowptr[N_NODES] = N_EDGES;
    __syncthreads();
    cnt[tid] = ex;                     // local cursor
    __syncthreads();
    for (int i = tid; i < cntE; i += 256) {
        int p = inLds ? ebuf[i] : pairbuf[base + i];
        int pos = atomicAdd(&cnt[(p >> 17) & 255], 1);
        csr[base + pos] = p & 0x1FFFF;
    }
}

// ---------------------------------------------------------------------------
// K1: t1 = half(x @ W1_nbr) ; r1 = x @ W1_root + b1      (128 -> 16 each)
// ---------------------------------------------------------------------------
__global__ __launch_bounds__(256) void k_transform1(
    const float* __restrict__ x,
    const float* __restrict__ W1n, const float* __restrict__ W1r,
    const float* __restrict__ b1,
    __half* __restrict__ t1, float* __restrict__ r1)
{
    __shared__ float sW[IN_CH * 32];   // [k][c]  c<16: nbr, c>=16: root
    __shared__ float sx[8 * IN_CH];

    for (int i = threadIdx.x; i < IN_CH * 32; i += 256) {
        int k = i >> 5, c = i & 31;
        sW[i] = (c < 16) ? W1n[k * 16 + c] : W1r[k * 16 + (c - 16)];
    }
    int node0 = blockIdx.x * 8;
    ((float4*)sx)[threadIdx.x] = ((const float4*)(x + (long)node0 * IN_CH))[threadIdx.x];
    __syncthreads();

    int c  = threadIdx.x & 31;
    int nl = threadIdx.x >> 5;
    const float* xr = &sx[nl * IN_CH];
    float acc = 0.f;
#pragma unroll 8
    for (int k = 0; k < IN_CH; ++k) acc += xr[k] * sW[k * 32 + c];

    int node = node0 + nl;
    if (c < 16) t1[node * 16 + c] = __float2half_rn(acc);
    else        r1[node * 16 + (c - 16)] = acc + b1[c - 16];
}

// ---------------------------------------------------------------------------
// Plane gather (16 channels, fp16 messages, fp32 accumulate). Used for the
// layer-1 table AND each 16-ch plane of layers 2/3 — each plane is 3.2 MB,
// resident in a 4 MB per-XCD L2 (the round-4 6.4 MB table thrashed at ~25%
// hit). 8 lanes/node (half2 channel pairs), 8-deep unroll for MLP; csr
// nontemporal (streamed once per pass).
// ---------------------------------------------------------------------------
__global__ __launch_bounds__(256) void k_gatherp(
    const int* __restrict__ rowptr, const int* __restrict__ csr,
    const __half2* __restrict__ t, float2* __restrict__ agg)
{
    int tid = blockIdx.x * 256 + threadIdx.x;      // exactly N_NODES*8 threads
    int n = tid >> 3, cp = tid & 7;
    int j = rowptr[n], end = rowptr[n + 1];
    float2 a0 = {0.f, 0.f}, a1 = {0.f, 0.f}, a2 = {0.f, 0.f}, a3 = {0.f, 0.f};
    for (; j + 7 < end; j += 8) {
        int s0 = __builtin_nontemporal_load(&csr[j]);
        int s1 = __builtin_nontemporal_load(&csr[j + 1]);
        int s2 = __builtin_nontemporal_load(&csr[j + 2]);
        int s3 = __builtin_nontemporal_load(&csr[j + 3]);
        int s4 = __builtin_nontemporal_load(&csr[j + 4]);
        int s5 = __builtin_nontemporal_load(&csr[j + 5]);
        int s6 = __builtin_nontemporal_load(&csr[j + 6]);
        int s7 = __builtin_nontemporal_load(&csr[j + 7]);
        float2 f0 = __half22float2(t[s0 * 8 + cp]);
        float2 f1 = __half22float2(t[s1 * 8 + cp]);
        float2 f2 = __half22float2(t[s2 * 8 + cp]);
        float2 f3 = __half22float2(t[s3 * 8 + cp]);
        float2 f4 = __half22float2(t[s4 * 8 + cp]);
        float2 f5 = __half22float2(t[s5 * 8 + cp]);
        float2 f6 = __half22float2(t[s6 * 8 + cp]);
        float2 f7 = __half22float2(t[s7 * 8 + cp]);
        a0.x += f0.x; a0.y += f0.y;  a1.x += f1.x; a1.y += f1.y;
        a2.x += f2.x; a2.y += f2.y;  a3.x += f3.x; a3.y += f3.y;
        a0.x += f4.x; a0.y += f4.y;  a1.x += f5.x; a1.y += f5.y;
        a2.x += f6.x; a2.y += f6.y;  a3.x += f7.x; a3.y += f7.y;
    }
    for (; j < end; ++j) {
        float2 f = __half22float2(t[__builtin_nontemporal_load(&csr[j]) * 8 + cp]);
        a0.x += f.x; a0.y += f.y;
    }
    float2 r;
    r.x = (a0.x + a1.x) + (a2.x + a3.x);
    r.y = (a0.y + a1.y) + (a2.y + a3.y);
    agg[n * 8 + cp] = r;
}

// ---------------------------------------------------------------------------
// K3: h1 = relu(r1 + aggA); t2 planes = half(h1 @ W2_nbr); r2 = h1 @ W2_root + b2
// ---------------------------------------------------------------------------
__global__ __launch_bounds__(256) void k_combine1_transform2(
    const float* __restrict__ r1, const float* __restrict__ aggA,
    const float* __restrict__ W2n, const float* __restrict__ W2r,
    const float* __restrict__ b2,
    __half* __restrict__ t2a, __half* __restrict__ t2b, float* __restrict__ r2)
{
    __shared__ float sW[16 * 64];   // [k][c]
    __shared__ float sh[4 * 16];

    for (int i = threadIdx.x; i < 16 * 64; i += 256) {
        int k = i >> 6, c = i & 63;
        sW[i] = (c < 32) ? W2n[k * 32 + c] : W2r[k * 32 + (c - 32)];
    }
    int node0 = blockIdx.x * 4;
    if (threadIdx.x < 64) {
        int idx = node0 * 16 + threadIdx.x;
        float v = r1[idx] + aggA[idx];
        sh[threadIdx.x] = v > 0.f ? v : 0.f;
    }
    __syncthreads();

    int c  = threadIdx.x & 63;
    int nl = threadIdx.x >> 6;
    const float* hr = &sh[nl * 16];
    float acc = 0.f;
#pragma unroll
    for (int k = 0; k < 16; ++k) acc += hr[k] * sW[k * 64 + c];

    int node = node0 + nl;
    if (c < 16)      t2a[node * 16 + c] = __float2half_rn(acc);
    else if (c < 32) t2b[node * 16 + (c - 16)] = __float2half_rn(acc);
    else             r2[node * 32 + (c - 32)] = acc + b2[c - 32];
}

// ---------------------------------------------------------------------------
// K5: h2 = relu(r2 + aggA|aggB); t3 planes = half(h2 @ W3_nbr); r3 = ... + b3
// t3/r3 alias t2/r2 — blocks read their own slice first, barrier, overwrite.
// ---------------------------------------------------------------------------
__global__ __launch_bounds__(256) void k_combine2_transform3(
    const float* __restrict__ r2,
    const float* __restrict__ aggA, const float* __restrict__ aggB,
    const float* __restrict__ W3n, const float* __restrict__ W3r,
    const float* __restrict__ b3,
    __half* __restrict__ t3a, __half* __restrict__ t3b, float* __restrict__ r3)
{
    __shared__ float sW[32 * 64];
    __shared__ float sh[4 * 32];

    for (int i = threadIdx.x; i < 32 * 64; i += 256) {
        int k = i >> 6, c = i & 63;
        sW[i] = (c < 32) ? W3n[k * 32 + c] : W3r[k * 32 + (c - 32)];
    }
    int node0 = blockIdx.x * 4;
    if (threadIdx.x < 128) {
        int nl2 = threadIdx.x >> 5, c2 = threadIdx.x & 31;
        int n = node0 + nl2;
        float a = (c2 < 16) ? aggA[n * 16 + c2] : aggB[n * 16 + (c2 - 16)];
        float v = r2[node0 * 32 + threadIdx.x] + a;
        sh[threadIdx.x] = v > 0.f ? v : 0.f;
    }
    __syncthreads();

    int c  = threadIdx.x & 63;
    int nl = threadIdx.x >> 6;
    const float* hr = &sh[nl * 32];
    float acc = 0.f;
#pragma unroll
    for (int k = 0; k < 32; ++k) acc += hr[k] * sW[k * 64 + c];

    int node = node0 + nl;
    if (c < 16)      t3a[node * 16 + c] = __float2half_rn(acc);
    else if (c < 32) t3b[node * 16 + (c - 16)] = __float2half_rn(acc);
    else             r3[node * 32 + (c - 32)] = acc + b3[c - 32];
}

// ---------------------------------------------------------------------------
// K7: h3 = relu(r3 + aggA|aggB); pooled[batch[n]] += h3[n]
// ---------------------------------------------------------------------------
__global__ __launch_bounds__(256) void k_combine3_pool(
    const float* __restrict__ r3,
    const float* __restrict__ aggA, const float* __restrict__ aggB,
    const int* __restrict__ batch, float* __restrict__ pooled)
{
    int tid = blockIdx.x * 256 + threadIdx.x;
    if (tid >= N_NODES * 32) return;
    int n = tid >> 5, c = tid & 31;
    float a = (c < 16) ? aggA[n * 16 + c] : aggB[n * 16 + (c - 16)];
    float v = r3[tid] + a;
    v = v > 0.f ? v : 0.f;
    atomicAdd(&pooled[batch[n] * 32 + c], v);
}

// ---------------------------------------------------------------------------
// K8: out = pooled @ Wlin + blin   (1000x32 @ 32x64)
// ---------------------------------------------------------------------------
__global__ __launch_bounds__(64) void k_final(
    const float* __restrict__ pooled, const float* __restrict__ Wlin,
    const float* __restrict__ blin, float* __restrict__ out)
{
    int g = blockIdx.x;
    int o = threadIdx.x;
    float acc = blin[o];
#pragma unroll
    for (int k = 0; k < 32; ++k) acc += pooled[g * 32 + k] * Wlin[k * 64 + o];
    out[g * 64 + o] = acc;
}

static inline char* align16(char* p) {
    return (char*)(((uintptr_t)p + 15) & ~(uintptr_t)15);
}

extern "C" void kernel_launch(void* const* d_in, const int* in_sizes, int n_in,
                              void* d_out, int out_size, void* d_ws, size_t ws_size,
                              hipStream_t stream) {
    const float* x     = (const float*)d_in[0];
    const int*   ei    = (const int*)d_in[1];
    const int*   batch = (const int*)d_in[2];
    const float* W1r   = (const float*)d_in[3];
    const float* W1n   = (const float*)d_in[4];
    const float* b1    = (const float*)d_in[5];
    const float* W2r   = (const float*)d_in[6];
    const float* W2n   = (const float*)d_in[7];
    const float* b2    = (const float*)d_in[8];
    const float* W3r   = (const float*)d_in[9];
    const float* W3n   = (const float*)d_in[10];
    const float* b3    = (const float*)d_in[11];
    const float* Wlin  = (const float*)d_in[12];
    const float* blin  = (const float*)d_in[13];
    float* out = (float*)d_out;

    // ---- workspace layout --------------------------------------------------
    // zero region: gcount[512] + pooled[32000 floats]       (one small memset)
    // boff[512] cursor[512] rowptr[100001] csr[3.2M ints]
    // pairbuf[3.2M ints, 12.8MB] -- aliases t1(half,3.2MB)+r1(f32,6.4MB)
    // t2a/t2b half planes 3.2MB each, r2 f32 12.8MB, aggA/aggB f32 6.4MB each.
    // t3a/t3b/r3 alias t2a/t2b/r2 (in-place).  Total ~58.5 MB.
    char* p = (char*)d_ws;
    int*   gcount = (int*)p;               p += 512 * 4;
    float* pooled = (float*)p;             p += (size_t)NUM_GRAPHS * 32 * 4;
    int*   boff   = (int*)p;               p += 512 * 4;
    int*   cursor = (int*)p;               p += 512 * 4;
    int*   rowptr = (int*)p;               p = align16(p + (N_NODES + 1) * 4);
    int*   csr    = (int*)p;               p += (size_t)N_EDGES * 4;
    int*   pairbuf= (int*)p;
    __half* t1    = (__half*)pairbuf;                                  // alias
    float*  r1    = (float*)((char*)pairbuf + (size_t)N_NODES * 16 * 2);
    p += (size_t)N_EDGES * 4;
    __half* t2a   = (__half*)p;            p += (size_t)N_NODES * 16 * 2;
    __half* t2b   = (__half*)p;            p += (size_t)N_NODES * 16 * 2;
    float*  r2    = (float*)p;             p += (size_t)N_NODES * 32 * 4;
    float*  aggA  = (float*)p;             p += (size_t)N_NODES * 16 * 4;
    float*  aggB  = (float*)p;
    __half* t3a   = t2a;  // in-place
    __half* t3b   = t2b;  // in-place
    float*  r3    = r2;   // in-place

    hipMemsetAsync(gcount, 0, (512 + (size_t)NUM_GRAPHS * 32) * 4, stream);

    // CSR build (bucketed, sorted writes)
    k_count_buckets<<<NBLK_BIN, 256, 0, stream>>>(ei, gcount);
    k_scan_buckets <<<1, 512, 0, stream>>>(gcount, boff, cursor);
    k_scatter_pairs<<<NBLK_BIN, 256, 0, stream>>>(ei, cursor, pairbuf);
    k_build_csr    <<<NB, 256, 0, stream>>>(gcount, boff, pairbuf, rowptr, csr);

    const int GG = N_NODES * 8 / 256;   // gather grid

    // Layer pipeline
    k_transform1<<<N_NODES / 8, 256, 0, stream>>>(x, W1n, W1r, b1, t1, r1);
    k_gatherp   <<<GG, 256, 0, stream>>>(rowptr, csr, (const __half2*)t1, (float2*)aggA);
    k_combine1_transform2<<<N_NODES / 4, 256, 0, stream>>>(r1, aggA, W2n, W2r, b2,
                                                           t2a, t2b, r2);
    k_gatherp   <<<GG, 256, 0, stream>>>(rowptr, csr, (const __half2*)t2a, (float2*)aggA);
    k_gatherp   <<<GG, 256, 0, stream>>>(rowptr, csr, (const __half2*)t2b, (float2*)aggB);
    k_combine2_transform3<<<N_NODES / 4, 256, 0, stream>>>(r2, aggA, aggB, W3n, W3r, b3,
                                                           t3a, t3b, r3);
    k_gatherp   <<<GG, 256, 0, stream>>>(rowptr, csr, (const __half2*)t3a, (float2*)aggA);
    k_gatherp   <<<GG, 256, 0, stream>>>(rowptr, csr, (const __half2*)t3b, (float2*)aggB);
    k_combine3_pool<<<N_NODES * 32 / 256, 256, 0, stream>>>(r3, aggA, aggB, batch, pooled);
    k_final     <<<NUM_GRAPHS, 64, 0, stream>>>(pooled, Wlin, blin, out);
}